// Round 2
// baseline (21931.082 us; speedup 1.0000x reference)
//
#include <hip/hip_runtime.h>
#include <hip/hip_bf16.h>

typedef __hip_bfloat16 bf16;
typedef short bf16x8 __attribute__((ext_vector_type(8)));
typedef float f32x4 __attribute__((ext_vector_type(4)));

#define MFMA16(A, B, C) __builtin_amdgcn_mfma_f32_16x16x32_bf16(A, B, C, 0, 0, 0)

__device__ __forceinline__ float sigf(float x) { return 1.f / (1.f + __expf(-x)); }
__device__ __forceinline__ float tanh_fast(float x) { return 2.f / (1.f + __expf(-2.f * x)) - 1.f; }

// ---------------- pack x: f32 [B*T][264] -> bf16 [B*T][256] ----------------
__global__ __launch_bounds__(256) void pack_x_k(const float* __restrict__ x,
                                                bf16* __restrict__ xbf) {
  const long idx = ((long)blockIdx.x * 256 + threadIdx.x) * 4;  // element idx
  const long row = idx >> 8;
  const int f = (int)(idx & 255);
  const float4 v = *(const float4*)(x + row * 264 + f);
  bf16* p = xbf + row * 256 + f;
  p[0] = __float2bfloat16(v.x);
  p[1] = __float2bfloat16(v.y);
  p[2] = __float2bfloat16(v.z);
  p[3] = __float2bfloat16(v.w);
}

// ---------------- transpose+cast: WT[n][k] = bf16(W[k][n]) ----------------
__global__ __launch_bounds__(256) void transpose_k(const float* __restrict__ W,
                                                   bf16* __restrict__ WT,
                                                   int K, int N) {
  __shared__ bf16 tile[32][33];
  const int n0 = blockIdx.x * 32, k0 = blockIdx.y * 32;
  const int c = threadIdx.x & 31, r0 = threadIdx.x >> 5;
  for (int i = 0; i < 4; ++i) {
    int r = r0 + 8 * i;
    tile[r][c] = __float2bfloat16(W[(long)(k0 + r) * N + (n0 + c)]);
  }
  __syncthreads();
  for (int i = 0; i < 4; ++i) {
    int r = r0 + 8 * i;
    WT[(long)(n0 + r) * K + (k0 + c)] = tile[c][r];
  }
}

// ---------------- persistent fused LSTM layer ----------------
// 64 WGs x 256 threads. WG w owns h-cols [w*8, w*8+8) -> 32 gate cols
// (8 per gate). Per step: z = x_t @ Wi + h_{t-1} @ Wh (+bias in gate phase),
// MFMA 16x16x32 bf16 fp32-accum; c-state in registers; device-scope barrier.
__global__ __launch_bounds__(256) void lstm_fused_k(
    const bf16* __restrict__ xseq, int x_stride, int K_in,
    const bf16* __restrict__ WiT,    // [2048][K_in]  (n-major)
    const bf16* __restrict__ WhT,    // [2048][512]   (n-major)
    const float* __restrict__ bias,  // [2048] f32
    bf16* __restrict__ hdb,          // [2][64][512] double buffer (buf1 zeroed)
    bf16* __restrict__ hseq_out,     // [64*512][512] or nullptr
    unsigned int* __restrict__ ctr)  // zeroed arrival counter
{
  __shared__ short Whs[32 * 520];  // 32 gate rows x 512 k, pad +8 (33.3 KB)
  __shared__ float zs[32 * 66];    // z staging [gatecol j][b], pad 66 (8.4 KB)

  const int w = blockIdx.x;
  const int tid = threadIdx.x;
  const int lane = tid & 63;
  const int wv = tid >> 6;   // wave = M-tile (16 batch rows)
  const int q = lane >> 4;   // k-chunk selector
  const int r = lane & 15;

  // Wh slice -> LDS once (reused all 512 steps)
  for (int idx = tid; idx < 32 * 64; idx += 256) {
    const int j = idx >> 6, kc = idx & 63;
    const int zc = (j >> 3) * 512 + w * 8 + (j & 7);
    *(bf16x8*)(Whs + j * 520 + kc * 8) =
        *(const bf16x8*)(WhT + (long)zc * 512 + kc * 8);
  }

  // per-lane invariants
  const int m = wv * 16 + r;  // batch row this lane feeds A-fragments for
  const int zc0 = (r >> 3) * 512 + w * 8 + (r & 7);        // n-tile 0 gate col
  const int zc1 = (2 + (r >> 3)) * 512 + w * 8 + (r & 7);  // n-tile 1 gate col
  const bf16* wi0p = WiT + (long)zc0 * K_in;
  const bf16* wi1p = WiT + (long)zc1 * K_in;
  const short* wh0p = Whs + r * 520;
  const short* wh1p = Whs + (16 + r) * 520;
  const bf16* xrow0 = xseq + (long)m * 512 * x_stride;

  // gate-phase invariants: thread handles (b=gb, c=gc0) and (gb, gc0+4)
  const int gb = tid & 63;
  const int gc0 = tid >> 6;
  float bias_r[2][4];
  for (int s = 0; s < 2; ++s)
    for (int g = 0; g < 4; ++g)
      bias_r[s][g] = bias[g * 512 + w * 8 + gc0 + 4 * s];
  float creg[2] = {0.f, 0.f};  // c0 = 0 (matches reference)

  __syncthreads();

  const unsigned int nwg = gridDim.x;
  for (int t = 0; t < 512; ++t) {
    const bf16* hprev = hdb + ((t & 1) ^ 1) * 32768;  // h[t-1]; t=0 -> zeros
    f32x4 acc0 = {0.f, 0.f, 0.f, 0.f};
    f32x4 acc1 = {0.f, 0.f, 0.f, 0.f};

    // input-transform part: x_t @ Wi (B-fragments from global/L2)
    const bf16* arow = xrow0 + (long)t * x_stride;
    for (int kk = 0; kk < K_in; kk += 32) {
      bf16x8 af = *(const bf16x8*)(arow + kk + q * 8);
      bf16x8 b0 = *(const bf16x8*)(wi0p + kk + q * 8);
      bf16x8 b1 = *(const bf16x8*)(wi1p + kk + q * 8);
      acc0 = MFMA16(af, b0, acc0);
      acc1 = MFMA16(af, b1, acc1);
    }
    // recurrent part: h_{t-1} @ Wh (B-fragments from LDS)
    const bf16* hrow = hprev + m * 512;
    for (int kk = 0; kk < 512; kk += 32) {
      bf16x8 af = *(const bf16x8*)(hrow + kk + q * 8);
      bf16x8 b0 = *(const bf16x8*)(wh0p + kk + q * 8);
      bf16x8 b1 = *(const bf16x8*)(wh1p + kk + q * 8);
      acc0 = MFMA16(af, b0, acc0);
      acc1 = MFMA16(af, b1, acc1);
    }

    // D-layout: row(b) = wv*16 + q*4 + i, col(n) = ntile*16 + r  [m89-verified]
    {
      const int brow = wv * 16 + q * 4;
      for (int i = 0; i < 4; ++i) zs[r * 66 + brow + i] = acc0[i];
      for (int i = 0; i < 4; ++i) zs[(16 + r) * 66 + brow + i] = acc1[i];
    }
    __syncthreads();

    // gate phase: zs rows j = g*8 + c; i,f,g,o = gates 0..3
    for (int s = 0; s < 2; ++s) {
      const int c = gc0 + 4 * s;
      const int hc = w * 8 + c;
      const float zi = zs[(c)*66 + gb] + bias_r[s][0];
      const float zf = zs[(8 + c) * 66 + gb] + bias_r[s][1];
      const float zg = zs[(16 + c) * 66 + gb] + bias_r[s][2];
      const float zo = zs[(24 + c) * 66 + gb] + bias_r[s][3];
      const float cnew = sigf(zf) * creg[s] + sigf(zi) * tanh_fast(zg);
      const float hnew = sigf(zo) * tanh_fast(cnew);
      creg[s] = cnew;
      const bf16 hb = __float2bfloat16(hnew);
      hdb[(t & 1) * 32768 + gb * 512 + hc] = hb;
      if (hseq_out) hseq_out[((long)(gb * 512 + t)) * 512 + hc] = hb;
    }

    // device-scope barrier: release h[t], acquire everyone's h[t]
    __threadfence();
    __syncthreads();
    if (tid == 0) {
      __hip_atomic_fetch_add(ctr, 1u, __ATOMIC_RELEASE, __HIP_MEMORY_SCOPE_AGENT);
      const unsigned int target = nwg * (unsigned int)(t + 1);
      while (__hip_atomic_load(ctr, __ATOMIC_ACQUIRE, __HIP_MEMORY_SCOPE_AGENT) < target) {
        __builtin_amdgcn_s_sleep(2);
      }
    }
    __syncthreads();
    __threadfence();  // acquire side: invalidate caches so hprev reads are fresh
  }
}

// ---------------- dense head: concat -> 512 -> 256 -> 64 -> sigmoid ----------
__global__ __launch_bounds__(256) void head_k(
    const bf16* __restrict__ hlast,  // [64][512] = h2 double-buffer slot 1
    const float* __restrict__ x,     // for last 8 features at t=511
    const float* __restrict__ Wd0, const float* __restrict__ bd0,
    const float* __restrict__ Wd1, const float* __restrict__ bd1,
    const float* __restrict__ Wf, const float* __restrict__ bfv,
    float* __restrict__ out) {
  const int b = blockIdx.x, tid = threadIdx.x;
  __shared__ float in0[520];
  __shared__ float d0s[512];
  __shared__ float d1s[256];
  for (int k = tid; k < 512; k += 256) in0[k] = __bfloat162float(hlast[b * 512 + k]);
  if (tid < 8) in0[512 + tid] = x[((long)(b * 512 + 511)) * 264 + 256 + tid];
  __syncthreads();
  for (int j = tid; j < 512; j += 256) {
    float a = bd0[j];
    for (int k = 0; k < 520; ++k) a += in0[k] * Wd0[(long)k * 512 + j];
    d0s[j] = fmaxf(a, 0.f);
  }
  __syncthreads();
  if (tid < 256) {
    const int j = tid;
    float a = bd1[j];
    for (int k = 0; k < 512; ++k) a += d0s[k] * Wd1[(long)k * 256 + j];
    d1s[j] = fmaxf(a, 0.f);
  }
  __syncthreads();
  if (tid < 64) {
    const int j = tid;
    float a = bfv[j];
    for (int k = 0; k < 256; ++k) a += d1s[k] * Wf[(long)k * 64 + j];
    out[b * 64 + j] = sigf(a);
  }
}

extern "C" void kernel_launch(void* const* d_in, const int* in_sizes, int n_in,
                              void* d_out, int out_size, void* d_ws, size_t ws_size,
                              hipStream_t stream) {
  const float* x   = (const float*)d_in[0];
  const float* Wi0 = (const float*)d_in[1];
  const float* Wh0 = (const float*)d_in[2];
  const float* b0  = (const float*)d_in[3];
  const float* Wi1 = (const float*)d_in[4];
  const float* Wh1 = (const float*)d_in[5];
  const float* b1  = (const float*)d_in[6];
  const float* Wd0 = (const float*)d_in[7];
  const float* bd0 = (const float*)d_in[8];
  const float* Wd1 = (const float*)d_in[9];
  const float* bd1 = (const float*)d_in[10];
  const float* Wf  = (const float*)d_in[11];
  const float* bf_ = (const float*)d_in[12];
  float* out = (float*)d_out;

  char* ws = (char*)d_ws;
  size_t off = 0;
  auto carve = [&](size_t bytes) {
    void* p = ws + off;
    off += (bytes + 255) & ~(size_t)255;
    return p;
  };
  unsigned int* ctr = (unsigned int*)carve(8);  // [0]=layer1, [1]=layer2
  bf16* h1db = (bf16*)carve(2 * 64 * 512 * 2);
  bf16* h2db = (bf16*)carve(2 * 64 * 512 * 2);
  const size_t zero_bytes = off;  // ctr + both h dbufs
  bf16* xbf  = (bf16*)carve((size_t)64 * 512 * 256 * 2);
  bf16* WiT0 = (bf16*)carve((size_t)2048 * 256 * 2);
  bf16* WhT0 = (bf16*)carve((size_t)2048 * 512 * 2);
  bf16* WiT1 = (bf16*)carve((size_t)2048 * 512 * 2);
  bf16* WhT1 = (bf16*)carve((size_t)2048 * 512 * 2);
  bf16* h1seq = (bf16*)carve((size_t)32768 * 512 * 2);  // layer-1 h sequence

  hipMemsetAsync(d_ws, 0, zero_bytes, stream);

  pack_x_k<<<8192, 256, 0, stream>>>(x, xbf);
  transpose_k<<<dim3(2048 / 32, 256 / 32), 256, 0, stream>>>(Wi0, WiT0, 256, 2048);
  transpose_k<<<dim3(2048 / 32, 512 / 32), 256, 0, stream>>>(Wh0, WhT0, 512, 2048);
  transpose_k<<<dim3(2048 / 32, 512 / 32), 256, 0, stream>>>(Wi1, WiT1, 512, 2048);
  transpose_k<<<dim3(2048 / 32, 512 / 32), 256, 0, stream>>>(Wh1, WhT1, 512, 2048);

  // layer 1: packed x, K=256
  lstm_fused_k<<<64, 256, 0, stream>>>(xbf, 256, 256, WiT0, WhT0, b0, h1db, h1seq, ctr);
  // layer 2: input = layer-1 h sequence
  lstm_fused_k<<<64, 256, 0, stream>>>(h1seq, 512, 512, WiT1, WhT1, b1, h2db, nullptr, ctr + 1);

  // head reads h2[t=511] which lives in double-buffer slot (511 & 1) = 1
  head_k<<<64, 256, 0, stream>>>(h2db + 32768, x, Wd0, bd0, Wd1, bd1, Wf, bf_, out);
}

// Round 3
// 5533.205 us; speedup vs baseline: 3.9635x; 3.9635x over previous
//
#include <hip/hip_runtime.h>
#include <hip/hip_bf16.h>

typedef __hip_bfloat16 bf16;
typedef short bf16x8 __attribute__((ext_vector_type(8)));
typedef float f32x4 __attribute__((ext_vector_type(4)));
typedef unsigned long long u64;

#define MFMA16(A, B, C) __builtin_amdgcn_mfma_f32_16x16x32_bf16(A, B, C, 0, 0, 0)

__device__ __forceinline__ float sigf(float x) { return 1.f / (1.f + __expf(-x)); }
__device__ __forceinline__ float tanh_fast(float x) { return 2.f / (1.f + __expf(-2.f * x)) - 1.f; }

// agent-scope (cross-XCD coherent) 16B h-load: 2x dwordx2 at coherence point,
// compiler-tracked vmcnt, no cache pollution / no buffer_inv anywhere.
__device__ __forceinline__ bf16x8 ld_h16(const bf16* p) {
  u64 lo = __hip_atomic_load((const u64*)p, __ATOMIC_RELAXED, __HIP_MEMORY_SCOPE_AGENT);
  u64 hi = __hip_atomic_load((const u64*)p + 1, __ATOMIC_RELAXED, __HIP_MEMORY_SCOPE_AGENT);
  union { u64 q[2]; bf16x8 v; } u;
  u.q[0] = lo; u.q[1] = hi;
  return u.v;
}
__device__ __forceinline__ void st_h16(bf16* p, const bf16* lds_src) {
  u64 lo = *(const u64*)(lds_src);
  u64 hi = *(const u64*)(lds_src + 4);
  __hip_atomic_store((u64*)p, lo, __ATOMIC_RELAXED, __HIP_MEMORY_SCOPE_AGENT);
  __hip_atomic_store((u64*)p + 1, hi, __ATOMIC_RELAXED, __HIP_MEMORY_SCOPE_AGENT);
}
__device__ __forceinline__ void waitctr(unsigned int* c, unsigned int target) {
  while (__hip_atomic_load(c, __ATOMIC_RELAXED, __HIP_MEMORY_SCOPE_AGENT) < target)
    __builtin_amdgcn_s_sleep(1);
}

// ---------------- pack x: f32 [B*T][264] -> bf16 [B*T][256] ----------------
__global__ __launch_bounds__(256) void pack_x_k(const float* __restrict__ x,
                                                bf16* __restrict__ xbf) {
  const long idx = ((long)blockIdx.x * 256 + threadIdx.x) * 4;
  const long row = idx >> 8;
  const int f = (int)(idx & 255);
  const float4 v = *(const float4*)(x + row * 264 + f);
  bf16* p = xbf + row * 256 + f;
  p[0] = __float2bfloat16(v.x);
  p[1] = __float2bfloat16(v.y);
  p[2] = __float2bfloat16(v.z);
  p[3] = __float2bfloat16(v.w);
}

// ---------------- transpose+cast: WT[n][k] = bf16(W[k][n]) ----------------
__global__ __launch_bounds__(256) void transpose_k(const float* __restrict__ W,
                                                   bf16* __restrict__ WT,
                                                   int K, int N) {
  __shared__ bf16 tile[32][33];
  const int n0 = blockIdx.x * 32, k0 = blockIdx.y * 32;
  const int c = threadIdx.x & 31, r0 = threadIdx.x >> 5;
  for (int i = 0; i < 4; ++i) {
    int r = r0 + 8 * i;
    tile[r][c] = __float2bfloat16(W[(long)(k0 + r) * N + (n0 + c)]);
  }
  __syncthreads();
  for (int i = 0; i < 4; ++i) {
    int r = r0 + 8 * i;
    WT[(long)(n0 + r) * K + (k0 + c)] = tile[c][r];
  }
}

// ---------------- fused 2-layer persistent LSTM, wavefront-pipelined --------
// 128 WGs x 256 thr. layer = blk>>6, w = blk&63 owns h-cols [8w,8w+8).
// h history: hseq[t][b][512] (t-major). Layer-0 consumes xbf, produces h1seq;
// layer-1 consumes h1seq (as soon as ctr0 >= 64(t+1)), produces h2seq.
// All h traffic via agent-scope atomics; weights live in LDS; NO fences.
__global__ __launch_bounds__(256) void lstm2_fused_k(
    const bf16* __restrict__ xbf,
    const bf16* __restrict__ WiT0, const bf16* __restrict__ WhT0,
    const float* __restrict__ bias0,
    const bf16* __restrict__ WiT1, const bf16* __restrict__ WhT1,
    const float* __restrict__ bias1,
    bf16* __restrict__ h1seq, bf16* __restrict__ h2seq,
    unsigned int* __restrict__ ctr)  // [0]=layer0 arrivals, [1]=layer1
{
  __shared__ short Wis[32 * 520];   // Wi slice: 32 gate-cols x K_in (33.3 KB)
  __shared__ short Whs[32 * 520];   // Wh slice: 32 gate-cols x 512  (33.3 KB)
  __shared__ float zs[32 * 66];     // z staging [gatecol][b] (8.4 KB)
  __shared__ bf16 hstage[64 * 8];   // h row-chunks for 16B stores (1 KB)

  const int layer = blockIdx.x >> 6;
  const int w = blockIdx.x & 63;
  const int tid = threadIdx.x;
  const int lane = tid & 63;
  const int wv = tid >> 6;
  const int q = lane >> 4;
  const int r = lane & 15;

  const int K_in = layer ? 512 : 256;
  const bf16* WiT = layer ? WiT1 : WiT0;
  const bf16* WhT = layer ? WhT1 : WhT0;
  const float* bias = layer ? bias1 : bias0;
  const bf16* hin = h1seq;              // layer-1 x-part source
  const bf16* hprevseq = layer ? h2seq : h1seq;
  bf16* hout = layer ? h2seq : h1seq;
  unsigned int* my_ctr = ctr + layer;

  // ---- stage weight slices into LDS (reused all 512 steps) ----
  for (int idx = tid; idx < 32 * 64; idx += 256) {  // Wh: 32 rows x 64 chunks
    const int j = idx >> 6, kc = idx & 63;
    const int zc = (j >> 3) * 512 + w * 8 + (j & 7);
    *(bf16x8*)(Whs + j * 520 + kc * 8) = *(const bf16x8*)(WhT + (long)zc * 512 + kc * 8);
  }
  const int csh = layer ? 6 : 5;           // chunks per row = K_in/8
  const int cmask = (1 << csh) - 1;
  for (int idx = tid; idx < (32 << csh); idx += 256) {  // Wi slice
    const int j = idx >> csh, kc = idx & cmask;
    const int zc = (j >> 3) * 512 + w * 8 + (j & 7);
    *(bf16x8*)(Wis + j * 520 + kc * 8) = *(const bf16x8*)(WiT + (long)zc * K_in + kc * 8);
  }

  // per-lane invariants
  const int m = wv * 16 + r;                 // batch row for A-fragments
  const short* wi0p = Wis + r * 520;
  const short* wi1p = Wis + (16 + r) * 520;
  const short* wh0p = Whs + r * 520;
  const short* wh1p = Whs + (16 + r) * 520;

  // gate-phase invariants
  const int gb = tid & 63;
  const int gc0 = tid >> 6;
  float bias_r[2][4];
  for (int s = 0; s < 2; ++s)
    for (int g = 0; g < 4; ++g)
      bias_r[s][g] = bias[g * 512 + w * 8 + gc0 + 4 * s];
  float creg[2] = {0.f, 0.f};

  __syncthreads();

  for (int t = 0; t < 512; ++t) {
    // ---- top-of-step waits (tid 0 only; relaxed polls, no cache inv) ----
    if (tid == 0) {
      if (layer == 0) {
        if (t > 0) waitctr(ctr, 64u * (unsigned)t);           // others' h1[t-1]
      } else {
        waitctr(ctr, 64u * (unsigned)(t + 1));                // h1[t] ready
        if (t > 0) waitctr(ctr + 1, 64u * (unsigned)t);       // others' h2[t-1]
      }
    }
    __syncthreads();

    f32x4 acc0 = {0.f, 0.f, 0.f, 0.f};
    f32x4 acc1 = {0.f, 0.f, 0.f, 0.f};

    // ---- x-part: layer0 cached loads of xbf, layer1 agent loads of h1[t] ----
    if (layer == 0) {
      const bf16* arow = xbf + ((long)m * 512 + t) * 256;
      for (int kk = 0; kk < 256; kk += 32) {
        bf16x8 af = *(const bf16x8*)(arow + kk + q * 8);
        bf16x8 b0 = *(const bf16x8*)(wi0p + kk + q * 8);
        bf16x8 b1 = *(const bf16x8*)(wi1p + kk + q * 8);
        acc0 = MFMA16(af, b0, acc0);
        acc1 = MFMA16(af, b1, acc1);
      }
    } else {
      const bf16* arow = hin + ((long)t * 64 + m) * 512;
      for (int kk = 0; kk < 512; kk += 32) {
        bf16x8 af = ld_h16(arow + kk + q * 8);
        bf16x8 b0 = *(const bf16x8*)(wi0p + kk + q * 8);
        bf16x8 b1 = *(const bf16x8*)(wi1p + kk + q * 8);
        acc0 = MFMA16(af, b0, acc0);
        acc1 = MFMA16(af, b1, acc1);
      }
    }
    // ---- h-part: h[t-1] via agent loads (skip at t=0: h(-1)=0) ----
    if (t > 0) {
      const bf16* hrow = hprevseq + ((long)(t - 1) * 64 + m) * 512;
      for (int kk = 0; kk < 512; kk += 32) {
        bf16x8 af = ld_h16(hrow + kk + q * 8);
        bf16x8 b0 = *(const bf16x8*)(wh0p + kk + q * 8);
        bf16x8 b1 = *(const bf16x8*)(wh1p + kk + q * 8);
        acc0 = MFMA16(af, b0, acc0);
        acc1 = MFMA16(af, b1, acc1);
      }
    }

    // D-layout: row(b)=wv*16+q*4+i, col(n)=ntile*16+r  [m89-verified]
    {
      const int brow = wv * 16 + q * 4;
      for (int i = 0; i < 4; ++i) zs[r * 66 + brow + i] = acc0[i];
      for (int i = 0; i < 4; ++i) zs[(16 + r) * 66 + brow + i] = acc1[i];
    }
    __syncthreads();

    // ---- gates: zs rows j = g*8 + c ----
    for (int s = 0; s < 2; ++s) {
      const int c = gc0 + 4 * s;
      const float zi = zs[(c)*66 + gb] + bias_r[s][0];
      const float zf = zs[(8 + c) * 66 + gb] + bias_r[s][1];
      const float zg = zs[(16 + c) * 66 + gb] + bias_r[s][2];
      const float zo = zs[(24 + c) * 66 + gb] + bias_r[s][3];
      const float cnew = sigf(zf) * creg[s] + sigf(zi) * tanh_fast(zg);
      const float hnew = sigf(zo) * tanh_fast(cnew);
      creg[s] = cnew;
      hstage[gb * 8 + c] = __float2bfloat16(hnew);
    }
    __syncthreads();

    // ---- publish h[t]: 16B agent stores, one per batch row ----
    if (tid < 64) st_h16(hout + ((long)t * 64 + tid) * 512 + w * 8, hstage + tid * 8);
    __syncthreads();  // drains vmcnt(0) for the storing wave before arrival
    if (tid == 0)
      __hip_atomic_fetch_add(my_ctr, 1u, __ATOMIC_RELAXED, __HIP_MEMORY_SCOPE_AGENT);
  }
}

// ---------------- dense head: concat -> 512 -> 256 -> 64 -> sigmoid ----------
__global__ __launch_bounds__(256) void head_k(
    const bf16* __restrict__ hlast,  // h2seq[511] = [64][512]
    const float* __restrict__ x,
    const float* __restrict__ Wd0, const float* __restrict__ bd0,
    const float* __restrict__ Wd1, const float* __restrict__ bd1,
    const float* __restrict__ Wf, const float* __restrict__ bfv,
    float* __restrict__ out) {
  const int b = blockIdx.x, tid = threadIdx.x;
  __shared__ float in0[520];
  __shared__ float d0s[512];
  __shared__ float d1s[256];
  for (int k = tid; k < 512; k += 256) in0[k] = __bfloat162float(hlast[b * 512 + k]);
  if (tid < 8) in0[512 + tid] = x[((long)(b * 512 + 511)) * 264 + 256 + tid];
  __syncthreads();
  for (int j = tid; j < 512; j += 256) {
    float a = bd0[j];
    for (int k = 0; k < 520; ++k) a += in0[k] * Wd0[(long)k * 512 + j];
    d0s[j] = fmaxf(a, 0.f);
  }
  __syncthreads();
  if (tid < 256) {
    const int j = tid;
    float a = bd1[j];
    for (int k = 0; k < 512; ++k) a += d0s[k] * Wd1[(long)k * 256 + j];
    d1s[j] = fmaxf(a, 0.f);
  }
  __syncthreads();
  if (tid < 64) {
    const int j = tid;
    float a = bfv[j];
    for (int k = 0; k < 256; ++k) a += d1s[k] * Wf[(long)k * 64 + j];
    out[b * 64 + j] = sigf(a);
  }
}

extern "C" void kernel_launch(void* const* d_in, const int* in_sizes, int n_in,
                              void* d_out, int out_size, void* d_ws, size_t ws_size,
                              hipStream_t stream) {
  const float* x   = (const float*)d_in[0];
  const float* Wi0 = (const float*)d_in[1];
  const float* Wh0 = (const float*)d_in[2];
  const float* b0  = (const float*)d_in[3];
  const float* Wi1 = (const float*)d_in[4];
  const float* Wh1 = (const float*)d_in[5];
  const float* b1  = (const float*)d_in[6];
  const float* Wd0 = (const float*)d_in[7];
  const float* bd0 = (const float*)d_in[8];
  const float* Wd1 = (const float*)d_in[9];
  const float* bd1 = (const float*)d_in[10];
  const float* Wf  = (const float*)d_in[11];
  const float* bf_ = (const float*)d_in[12];
  float* out = (float*)d_out;

  char* ws = (char*)d_ws;
  size_t off = 0;
  auto carve = [&](size_t bytes) {
    void* p = ws + off;
    off += (bytes + 255) & ~(size_t)255;
    return p;
  };
  unsigned int* ctr = (unsigned int*)carve(8);  // [0]=layer0, [1]=layer1
  const size_t zero_bytes = off;
  bf16* xbf  = (bf16*)carve((size_t)64 * 512 * 256 * 2);
  bf16* WiT0 = (bf16*)carve((size_t)2048 * 256 * 2);
  bf16* WhT0 = (bf16*)carve((size_t)2048 * 512 * 2);
  bf16* WiT1 = (bf16*)carve((size_t)2048 * 512 * 2);
  bf16* WhT1 = (bf16*)carve((size_t)2048 * 512 * 2);
  bf16* h1seq = (bf16*)carve((size_t)512 * 64 * 512 * 2);  // [t][b][512]
  bf16* h2seq = (bf16*)carve((size_t)512 * 64 * 512 * 2);  // [t][b][512]

  hipMemsetAsync(d_ws, 0, zero_bytes, stream);

  pack_x_k<<<8192, 256, 0, stream>>>(x, xbf);
  transpose_k<<<dim3(2048 / 32, 256 / 32), 256, 0, stream>>>(Wi0, WiT0, 256, 2048);
  transpose_k<<<dim3(2048 / 32, 512 / 32), 256, 0, stream>>>(Wh0, WhT0, 512, 2048);
  transpose_k<<<dim3(2048 / 32, 512 / 32), 256, 0, stream>>>(Wi1, WiT1, 512, 2048);
  transpose_k<<<dim3(2048 / 32, 512 / 32), 256, 0, stream>>>(Wh1, WhT1, 512, 2048);

  lstm2_fused_k<<<128, 256, 0, stream>>>(xbf, WiT0, WhT0, b0, WiT1, WhT1, b1,
                                         h1seq, h2seq, ctr);

  head_k<<<64, 256, 0, stream>>>(h2seq + (size_t)511 * 64 * 512, x,
                                 Wd0, bd0, Wd1, bd1, Wf, bf_, out);
}